// Round 1
// baseline (1897.994 us; speedup 1.0000x reference)
//
#include <hip/hip_runtime.h>
#include <math.h>

// Problem constants
#define NBATCH 8
#define NC 256      // IN_C == OUT_C
#define ND 32       // QK_C
#define SN 4096     // H*W

// Workspace layout (float offsets)
constexpr size_t V_OFF  = 0;                                   // 8*256*4096
constexpr size_t Q_OFF  = (size_t)NBATCH * NC * SN;            // 8388608
constexpr size_t K_OFF  = Q_OFF + (size_t)NBATCH * ND * SN;    // 9437184
constexpr size_t PM_OFF = K_OFF + (size_t)NBATCH * ND * SN;    // 10485760
constexpr size_t PS_OFF = PM_OFF + (size_t)NBATCH * 1024;      // 10493952
constexpr size_t GM_OFF = PS_OFF + (size_t)NBATCH * 1024;      // 10502144
constexpr size_t GZ_OFF = GM_OFF + NBATCH;                     // 10502152
// total ~10.5M floats = ~42 MB workspace

// ---------------------------------------------------------------------------
// Kernel 1: fused projections. Rows 0..255 -> v (W1), 256..287 -> q (W2),
// 288..319 -> k (W3). Tiled SGEMM: 64 rows x 64 cols per block, K=256.
// ---------------------------------------------------------------------------
__global__ __launch_bounds__(256) void proj_kernel(
    const float* __restrict__ x,
    const float* __restrict__ W1, const float* __restrict__ b1,
    const float* __restrict__ W2, const float* __restrict__ b2,
    const float* __restrict__ W3, const float* __restrict__ b3,
    float* __restrict__ ws)
{
  __shared__ float Ws[16][68];  // [kk][row], stride 68 keeps 16B alignment
  __shared__ float Xs[16][68];  // [kk][col]
  const int b  = blockIdx.z;
  const int r0 = blockIdx.y * 64;
  const int n0 = blockIdx.x * 64;
  const int t  = threadIdx.x;
  const int tr = t >> 4, tc = t & 15;
  const float* xb = x + (size_t)b * NC * SN;

  float acc[4][4] = {};
  for (int k0 = 0; k0 < NC; k0 += 16) {
    // W tile: Ws[kk][r] = Wrow(r0+r)[k0+kk]
    {
      int r  = t >> 2;
      int kk = (t & 3) * 4;
      int rg = r0 + r;
      const float* wrow = rg < 256 ? (W1 + (size_t)rg * NC)
                        : (rg < 288 ? (W2 + (size_t)(rg - 256) * NC)
                                    : (W3 + (size_t)(rg - 288) * NC));
      float4 w = *reinterpret_cast<const float4*>(wrow + k0 + kk);
      Ws[kk + 0][r] = w.x; Ws[kk + 1][r] = w.y;
      Ws[kk + 2][r] = w.z; Ws[kk + 3][r] = w.w;
    }
    // X tile: Xs[kk][n] = xb[(k0+kk)*SN + n0+n]
    {
      int kk = t >> 4;
      int nn = (t & 15) * 4;
      float4 xv = *reinterpret_cast<const float4*>(xb + (size_t)(k0 + kk) * SN + n0 + nn);
      *reinterpret_cast<float4*>(&Xs[kk][nn]) = xv;
    }
    __syncthreads();
#pragma unroll
    for (int kk = 0; kk < 16; ++kk) {
      float4 wv = *reinterpret_cast<const float4*>(&Ws[kk][tr * 4]);
      float4 xv = *reinterpret_cast<const float4*>(&Xs[kk][tc * 4]);
      float w[4] = {wv.x, wv.y, wv.z, wv.w};
      float xx[4] = {xv.x, xv.y, xv.z, xv.w};
#pragma unroll
      for (int i = 0; i < 4; ++i)
#pragma unroll
        for (int j = 0; j < 4; ++j) acc[i][j] += w[i] * xx[j];
    }
    __syncthreads();
  }
#pragma unroll
  for (int i = 0; i < 4; ++i) {
    int r = r0 + tr * 4 + i;
    float bias;
    float* orow;
    if (r < 256)      { bias = b1[r];       orow = ws + V_OFF + ((size_t)b * NC + r) * SN; }
    else if (r < 288) { bias = b2[r - 256]; orow = ws + Q_OFF + ((size_t)b * ND + (r - 256)) * SN; }
    else              { bias = b3[r - 288]; orow = ws + K_OFF + ((size_t)b * ND + (r - 288)) * SN; }
    float4 o;
    o.x = acc[i][0] + bias; o.y = acc[i][1] + bias;
    o.z = acc[i][2] + bias; o.w = acc[i][3] + bias;
    *reinterpret_cast<float4*>(orow + n0 + tc * 4) = o;
  }
}

// ---------------------------------------------------------------------------
// Kernel 2: per-tile (max, sum-exp) of scores = q^T k. Tile 128x128, K=32.
// Writes per-block partials (1024 per batch).
// ---------------------------------------------------------------------------
__global__ __launch_bounds__(256) void qk_stats_kernel(
    const float* __restrict__ ws, float* __restrict__ pm, float* __restrict__ psum)
{
  __shared__ float qs[32][128];
  __shared__ float ks[32][128];
  __shared__ float rm[256], rz[256];
  const int b  = blockIdx.z;
  const int n0 = blockIdx.y * 128;
  const int m0 = blockIdx.x * 128;
  const int t  = threadIdx.x;
  const float* qb = ws + Q_OFF + (size_t)b * ND * SN;
  const float* kb = ws + K_OFF + (size_t)b * ND * SN;
  {
    int d  = t >> 3;
    int c0 = (t & 7) * 16;
    const float* qrow = qb + (size_t)d * SN + n0;
    const float* krow = kb + (size_t)d * SN + m0;
#pragma unroll
    for (int u = 0; u < 16; u += 4) {
      *reinterpret_cast<float4*>(&qs[d][c0 + u]) = *reinterpret_cast<const float4*>(qrow + c0 + u);
      *reinterpret_cast<float4*>(&ks[d][c0 + u]) = *reinterpret_cast<const float4*>(krow + c0 + u);
    }
  }
  __syncthreads();
  const int tn = t >> 4, tm = t & 15;
  float s[8][8] = {};
#pragma unroll
  for (int d = 0; d < 32; ++d) {
    float qv[8], kv[8];
    *reinterpret_cast<float4*>(qv)     = *reinterpret_cast<const float4*>(&qs[d][tn * 4]);
    *reinterpret_cast<float4*>(qv + 4) = *reinterpret_cast<const float4*>(&qs[d][64 + tn * 4]);
    *reinterpret_cast<float4*>(kv)     = *reinterpret_cast<const float4*>(&ks[d][tm * 4]);
    *reinterpret_cast<float4*>(kv + 4) = *reinterpret_cast<const float4*>(&ks[d][64 + tm * 4]);
#pragma unroll
    for (int i = 0; i < 8; ++i)
#pragma unroll
      for (int j = 0; j < 8; ++j) s[i][j] += qv[i] * kv[j];
  }
  float mt = -1e30f;
#pragma unroll
  for (int i = 0; i < 8; ++i)
#pragma unroll
    for (int j = 0; j < 8; ++j) mt = fmaxf(mt, s[i][j]);
  float zt = 0.f;
#pragma unroll
  for (int i = 0; i < 8; ++i)
#pragma unroll
    for (int j = 0; j < 8; ++j) zt += __expf(s[i][j] - mt);

  rm[t] = mt; rz[t] = zt;
  __syncthreads();
  for (int off = 128; off > 0; off >>= 1) {
    if (t < off) {
      float m1 = rm[t], z1 = rz[t];
      float m2 = rm[t + off], z2 = rz[t + off];
      float M = fmaxf(m1, m2);
      rm[t] = M;
      rz[t] = z1 * __expf(m1 - M) + z2 * __expf(m2 - M);
    }
    __syncthreads();
  }
  if (t == 0) {
    int idx = (b * 32 + blockIdx.y) * 32 + blockIdx.x;
    pm[idx] = rm[0];
    psum[idx] = rz[0];
  }
}

// ---------------------------------------------------------------------------
// Kernel 3: combine 1024 partials per batch -> global max M, 1/Z.
// ---------------------------------------------------------------------------
__global__ __launch_bounds__(256) void reduce_kernel(float* __restrict__ ws)
{
  const int b = blockIdx.x;
  const float* pm = ws + PM_OFF + (size_t)b * 1024;
  const float* ps = ws + PS_OFF + (size_t)b * 1024;
  const int t = threadIdx.x;
  float m = -1e30f, z = 0.f;
  for (int i = t; i < 1024; i += 256) {
    float m2 = pm[i], z2 = ps[i];
    float M = fmaxf(m, m2);
    z = z * __expf(m - M) + z2 * __expf(m2 - M);
    m = M;
  }
  __shared__ float rm[256], rz[256];
  rm[t] = m; rz[t] = z;
  __syncthreads();
  for (int off = 128; off > 0; off >>= 1) {
    if (t < off) {
      float m1 = rm[t], z1 = rz[t];
      float m2 = rm[t + off], z2 = rz[t + off];
      float M = fmaxf(m1, m2);
      rm[t] = M;
      rz[t] = z1 * __expf(m1 - M) + z2 * __expf(m2 - M);
    }
    __syncthreads();
  }
  if (t == 0) {
    ws[GM_OFF + b] = rm[0];
    ws[GZ_OFF + b] = 1.0f / rz[0];
  }
}

// ---------------------------------------------------------------------------
// Kernel 4: Out[o,m] = sum_n v[o,n] * exp(qk[n,m]-M)/Z  + x[o,m]
// Block: 128 o-rows x 128 m-cols; loop n in chunks of 32; A-chunk recomputed
// in LDS from q,k.
// ---------------------------------------------------------------------------
__global__ __launch_bounds__(256) void out_kernel(
    const float* __restrict__ ws, const float* __restrict__ x, float* __restrict__ out)
{
  __shared__ float ks[32][128];   // k columns for this m-tile (resident)
  __shared__ float qs[32][32];    // q chunk [d][n]
  __shared__ float as[32][128];   // exp weights [n][m]
  __shared__ float vs[128][36];   // v chunk [o][n], padded
  const int b  = blockIdx.z;
  const int o0 = blockIdx.y * 128;
  const int m0 = blockIdx.x * 128;
  const int t  = threadIdx.x;
  const float* qb = ws + Q_OFF + (size_t)b * ND * SN;
  const float* kb = ws + K_OFF + (size_t)b * ND * SN;
  const float* vb = ws + V_OFF + (size_t)b * NC * SN;
  const float M    = ws[GM_OFF + b];
  const float invZ = ws[GZ_OFF + b];
  {
    int d  = t >> 3;
    int c0 = (t & 7) * 16;
    const float* krow = kb + (size_t)d * SN + m0;
#pragma unroll
    for (int u = 0; u < 16; u += 4)
      *reinterpret_cast<float4*>(&ks[d][c0 + u]) = *reinterpret_cast<const float4*>(krow + c0 + u);
  }
  __syncthreads();

  const int to = t >> 4, tm = t & 15;   // main acc 16x16 threads
  const int an = t >> 5, am = t & 31;   // A-compute: 8 x 32 threads
  float acc[8][8] = {};
  for (int n0 = 0; n0 < SN; n0 += 32) {
    // load q chunk (32d x 32n)
    {
      int d = t >> 3, nb = (t & 7) * 4;
      *reinterpret_cast<float4*>(&qs[d][nb]) =
          *reinterpret_cast<const float4*>(qb + (size_t)d * SN + n0 + nb);
    }
    // load v chunk: vs[o][nn] (128 o x 32 n)
    {
      int o = t >> 1, nb = (t & 1) * 16;
      const float* vrow = vb + (size_t)(o0 + o) * SN + n0 + nb;
#pragma unroll
      for (int u = 0; u < 16; u += 4)
        *reinterpret_cast<float4*>(&vs[o][nb + u]) = *reinterpret_cast<const float4*>(vrow + u);
    }
    __syncthreads();
    // A chunk: thread -> rows an*4..+3, cols am*4..+3
    {
      float sv[4][4] = {};
#pragma unroll
      for (int d = 0; d < 32; ++d) {
        float4 qv = *reinterpret_cast<const float4*>(&qs[d][an * 4]);
        float4 kv = *reinterpret_cast<const float4*>(&ks[d][am * 4]);
        float qa[4] = {qv.x, qv.y, qv.z, qv.w};
        float ka[4] = {kv.x, kv.y, kv.z, kv.w};
#pragma unroll
        for (int i = 0; i < 4; ++i)
#pragma unroll
          for (int j = 0; j < 4; ++j) sv[i][j] += qa[i] * ka[j];
      }
#pragma unroll
      for (int i = 0; i < 4; ++i) {
        float4 av;
        av.x = __expf(sv[i][0] - M) * invZ;
        av.y = __expf(sv[i][1] - M) * invZ;
        av.z = __expf(sv[i][2] - M) * invZ;
        av.w = __expf(sv[i][3] - M) * invZ;
        *reinterpret_cast<float4*>(&as[an * 4 + i][am * 4]) = av;
      }
    }
    __syncthreads();
    // accumulate: acc[i][j] += vs[o][nn] * as[nn][m]
#pragma unroll
    for (int nn = 0; nn < 32; ++nn) {
      float vv[8];
#pragma unroll
      for (int i = 0; i < 4; ++i) vv[i]     = vs[to * 4 + i][nn];
#pragma unroll
      for (int i = 0; i < 4; ++i) vv[4 + i] = vs[64 + to * 4 + i][nn];
      float av[8];
      *reinterpret_cast<float4*>(av)     = *reinterpret_cast<const float4*>(&as[nn][tm * 4]);
      *reinterpret_cast<float4*>(av + 4) = *reinterpret_cast<const float4*>(&as[nn][64 + tm * 4]);
#pragma unroll
      for (int i = 0; i < 8; ++i)
#pragma unroll
        for (int j = 0; j < 8; ++j) acc[i][j] += vv[i] * av[j];
    }
    __syncthreads();
  }
  // epilogue: + skip x
#pragma unroll
  for (int ih = 0; ih < 2; ++ih)
#pragma unroll
    for (int i = 0; i < 4; ++i) {
      int o = o0 + ih * 64 + to * 4 + i;
      const float* xrow = x + ((size_t)b * NC + o) * SN + m0;
      float* orow       = out + ((size_t)b * NC + o) * SN + m0;
#pragma unroll
      for (int jh = 0; jh < 2; ++jh) {
        float4 xv = *reinterpret_cast<const float4*>(xrow + jh * 64 + tm * 4);
        float4 ov;
        ov.x = acc[ih * 4 + i][jh * 4 + 0] + xv.x;
        ov.y = acc[ih * 4 + i][jh * 4 + 1] + xv.y;
        ov.z = acc[ih * 4 + i][jh * 4 + 2] + xv.z;
        ov.w = acc[ih * 4 + i][jh * 4 + 3] + xv.w;
        *reinterpret_cast<float4*>(orow + jh * 64 + tm * 4) = ov;
      }
    }
}

extern "C" void kernel_launch(void* const* d_in, const int* in_sizes, int n_in,
                              void* d_out, int out_size, void* d_ws, size_t ws_size,
                              hipStream_t stream)
{
  const float* x  = (const float*)d_in[0];
  const float* W1 = (const float*)d_in[1];
  const float* b1 = (const float*)d_in[2];
  const float* W2 = (const float*)d_in[3];
  const float* b2 = (const float*)d_in[4];
  const float* W3 = (const float*)d_in[5];
  const float* b3 = (const float*)d_in[6];
  float* ws  = (float*)d_ws;
  float* out = (float*)d_out;

  proj_kernel<<<dim3(64, 5, NBATCH), 256, 0, stream>>>(x, W1, b1, W2, b2, W3, b3, ws);
  qk_stats_kernel<<<dim3(32, 32, NBATCH), 256, 0, stream>>>(ws, ws + PM_OFF, ws + PS_OFF);
  reduce_kernel<<<NBATCH, 256, 0, stream>>>(ws);
  out_kernel<<<dim3(32, 2, NBATCH), 256, 0, stream>>>(ws, x, out);
}

// Round 2
// 308.318 us; speedup vs baseline: 6.1560x; 6.1560x over previous
//
#include <hip/hip_runtime.h>
#include <math.h>

#define NBATCH 8
#define NC 256
#define ND 32
#define SN 4096

// Workspace byte offsets
constexpr size_t VB_B = 0;                                   // 8*256*4096*2 = 16 MB bf16 V [b][o][n]
constexpr size_t QT_B = 16777216;                            // 8*4096*32*2 = 2 MB bf16 Q^T [b][n][d]
constexpr size_t KT_B = QT_B + 2097152;                      // 2 MB bf16 K^T [b][m][d]
constexpr size_t PM_B = KT_B + 2097152;                      // 8*1024 f32 partial max
constexpr size_t PS_B = PM_B + 32768;                        // 8*1024 f32 partial sumexp
constexpr size_t C_B  = PS_B + 32768;                        // 8 f32: C = M + ln Z

typedef __attribute__((ext_vector_type(8))) short short8;
typedef __attribute__((ext_vector_type(4))) float f32x4;

__device__ __forceinline__ unsigned bf16rne(float f) {
  unsigned u = __float_as_uint(f);
  return (u + 0x7fffu + ((u >> 16) & 1u)) >> 16;
}
__device__ __forceinline__ unsigned bfpack(float lo, float hi) {
  return bf16rne(lo) | (bf16rne(hi) << 16);
}

// ---------------------------------------------------------------------------
// Kernel 1: projections (fp32 compute, bf16 outputs; q/k transposed to [n][d])
// ---------------------------------------------------------------------------
__global__ __launch_bounds__(256) void proj_kernel(
    const float* __restrict__ x,
    const float* __restrict__ W1, const float* __restrict__ b1,
    const float* __restrict__ W2, const float* __restrict__ b2,
    const float* __restrict__ W3, const float* __restrict__ b3,
    char* __restrict__ wsb)
{
  __shared__ float Ws[16][68];
  __shared__ float Xs[16][68];
  const int b  = blockIdx.z;
  const int r0 = blockIdx.y * 64;
  const int n0 = blockIdx.x * 64;
  const int t  = threadIdx.x;
  const int tr = t >> 4, tc = t & 15;
  const float* xb = x + (size_t)b * NC * SN;
  ushort* vbuf  = (ushort*)(wsb + VB_B);
  ushort* qtbuf = (ushort*)(wsb + QT_B);
  ushort* ktbuf = (ushort*)(wsb + KT_B);

  float acc[4][4] = {};
  for (int k0 = 0; k0 < NC; k0 += 16) {
    {
      int r  = t >> 2;
      int kk = (t & 3) * 4;
      int rg = r0 + r;
      const float* wrow = rg < 256 ? (W1 + (size_t)rg * NC)
                        : (rg < 288 ? (W2 + (size_t)(rg - 256) * NC)
                                    : (W3 + (size_t)(rg - 288) * NC));
      float4 w = *reinterpret_cast<const float4*>(wrow + k0 + kk);
      Ws[kk + 0][r] = w.x; Ws[kk + 1][r] = w.y;
      Ws[kk + 2][r] = w.z; Ws[kk + 3][r] = w.w;
    }
    {
      int kk = t >> 4;
      int nn = (t & 15) * 4;
      float4 xv = *reinterpret_cast<const float4*>(xb + (size_t)(k0 + kk) * SN + n0 + nn);
      *reinterpret_cast<float4*>(&Xs[kk][nn]) = xv;
    }
    __syncthreads();
#pragma unroll
    for (int kk = 0; kk < 16; ++kk) {
      float4 wv = *reinterpret_cast<const float4*>(&Ws[kk][tr * 4]);
      float4 xv = *reinterpret_cast<const float4*>(&Xs[kk][tc * 4]);
      float w[4] = {wv.x, wv.y, wv.z, wv.w};
      float xx[4] = {xv.x, xv.y, xv.z, xv.w};
#pragma unroll
      for (int i = 0; i < 4; ++i)
#pragma unroll
        for (int j = 0; j < 4; ++j) acc[i][j] += w[i] * xx[j];
    }
    __syncthreads();
  }
#pragma unroll
  for (int i = 0; i < 4; ++i) {
    int r = r0 + tr * 4 + i;
    if (r < 256) {
      float bias = b1[r];
      ushort4 o;
      o.x = (ushort)bf16rne(acc[i][0] + bias);
      o.y = (ushort)bf16rne(acc[i][1] + bias);
      o.z = (ushort)bf16rne(acc[i][2] + bias);
      o.w = (ushort)bf16rne(acc[i][3] + bias);
      *reinterpret_cast<ushort4*>(vbuf + ((size_t)b * NC + r) * SN + n0 + tc * 4) = o;
    } else if (r < 288) {
      int d = r - 256;
      float bias = b2[d];
#pragma unroll
      for (int j = 0; j < 4; ++j)
        qtbuf[((size_t)b * SN + n0 + tc * 4 + j) * ND + d] = (ushort)bf16rne(acc[i][j] + bias);
    } else {
      int d = r - 288;
      float bias = b3[d];
#pragma unroll
      for (int j = 0; j < 4; ++j)
        ktbuf[((size_t)b * SN + n0 + tc * 4 + j) * ND + d] = (ushort)bf16rne(acc[i][j] + bias);
    }
  }
}

// ---------------------------------------------------------------------------
// Kernel 2: MFMA QK^T tile stats. 128n x 128m per block, 4 waves.
// ---------------------------------------------------------------------------
__global__ __launch_bounds__(256) void qk_stats(
    const char* __restrict__ wsb, float* __restrict__ pm, float* __restrict__ ps)
{
  __shared__ alignas(16) char qt_s[128 * 64];
  __shared__ alignas(16) char kt_s[128 * 64];
  __shared__ float rm[256], rz[256];
  const int b = blockIdx.z, n0 = blockIdx.y * 128, m0 = blockIdx.x * 128;
  const int t = threadIdx.x, w = t >> 6, lane = t & 63;
  const int l4 = lane >> 4, l16 = lane & 15;
  const ushort* qtb = (const ushort*)(wsb + QT_B) + (size_t)b * SN * ND;
  const ushort* ktb = (const ushort*)(wsb + KT_B) + (size_t)b * SN * ND;
  {
    int row = t >> 1, db = (t & 1) * 32;
#pragma unroll
    for (int i = 0; i < 2; ++i) {
      int b16 = db + i * 16;
      int dst = row * 64 + (b16 ^ ((row & 3) << 4));
      *reinterpret_cast<uint4*>(qt_s + dst) =
        *reinterpret_cast<const uint4*>(qtb + (size_t)(n0 + row) * ND + b16 / 2);
      *reinterpret_cast<uint4*>(kt_s + dst) =
        *reinterpret_cast<const uint4*>(ktb + (size_t)(m0 + row) * ND + b16 / 2);
    }
  }
  __syncthreads();
  const f32x4 zf = {0.f, 0.f, 0.f, 0.f};
  short8 bfr[2];
#pragma unroll
  for (int j = 0; j < 2; ++j) {
    int mm = (w * 2 + j) * 16 + l16;
    bfr[j] = *reinterpret_cast<const short8*>(kt_s + mm * 64 + ((l4 * 16) ^ ((mm & 3) << 4)));
  }
  f32x4 sfr[8][2];
#pragma unroll
  for (int i = 0; i < 8; ++i) {
    int nn = i * 16 + l16;
    short8 af = *reinterpret_cast<const short8*>(qt_s + nn * 64 + ((l4 * 16) ^ ((nn & 3) << 4)));
#pragma unroll
    for (int j = 0; j < 2; ++j)
      sfr[i][j] = __builtin_amdgcn_mfma_f32_16x16x32_bf16(af, bfr[j], zf, 0, 0, 0);
  }
  float mt = -1e30f;
#pragma unroll
  for (int i = 0; i < 8; ++i)
#pragma unroll
    for (int j = 0; j < 2; ++j)
#pragma unroll
      for (int r = 0; r < 4; ++r) mt = fmaxf(mt, sfr[i][j][r]);
  float zt = 0.f;
#pragma unroll
  for (int i = 0; i < 8; ++i)
#pragma unroll
    for (int j = 0; j < 2; ++j)
#pragma unroll
      for (int r = 0; r < 4; ++r) zt += __expf(sfr[i][j][r] - mt);

  rm[t] = mt; rz[t] = zt;
  __syncthreads();
  for (int off = 128; off > 0; off >>= 1) {
    if (t < off) {
      float m1 = rm[t], z1 = rz[t];
      float m2 = rm[t + off], z2 = rz[t + off];
      float M = fmaxf(m1, m2);
      rm[t] = M;
      rz[t] = z1 * __expf(m1 - M) + z2 * __expf(m2 - M);
    }
    __syncthreads();
  }
  if (t == 0) {
    int idx = (b * 32 + blockIdx.y) * 32 + blockIdx.x;
    pm[idx] = rm[0];
    ps[idx] = rz[0];
  }
}

// ---------------------------------------------------------------------------
// Kernel 3: combine partials -> C_b = M + ln(Z)
// ---------------------------------------------------------------------------
__global__ __launch_bounds__(256) void reduce_kernel(char* __restrict__ wsb)
{
  const int b = blockIdx.x;
  const float* pm = (const float*)(wsb + PM_B) + (size_t)b * 1024;
  const float* ps = (const float*)(wsb + PS_B) + (size_t)b * 1024;
  const int t = threadIdx.x;
  float m = -1e30f, z = 0.f;
  for (int i = t; i < 1024; i += 256) {
    float m2 = pm[i], z2 = ps[i];
    float M = fmaxf(m, m2);
    z = z * __expf(m - M) + z2 * __expf(m2 - M);
    m = M;
  }
  __shared__ float rm[256], rz[256];
  rm[t] = m; rz[t] = z;
  __syncthreads();
  for (int off = 128; off > 0; off >>= 1) {
    if (t < off) {
      float m1 = rm[t], z1 = rz[t];
      float m2 = rm[t + off], z2 = rz[t + off];
      float M = fmaxf(m1, m2);
      rm[t] = M;
      rz[t] = z1 * __expf(m1 - M) + z2 * __expf(m2 - M);
    }
    __syncthreads();
  }
  if (t == 0) ((float*)(wsb + C_B))[b] = rm[0] + logf(rz[0]);
}

// ---------------------------------------------------------------------------
// Kernel 4: MFMA attention output. Block = 128 o x 128 m, 4 waves, chunk n=64.
// a[n,m] = exp(S - C) recomputed in bf16 LDS; V fragments direct from global.
// ---------------------------------------------------------------------------
__global__ __launch_bounds__(256) void attn_out(
    const char* __restrict__ wsb, const float* __restrict__ x, float* __restrict__ out)
{
  __shared__ alignas(16) char kt_s[128 * 64];   // [m][d] bf16, swz (m&3)<<4
  __shared__ alignas(16) char qt_s[64 * 64];    // [n][d] bf16, swz (n&3)<<4
  __shared__ alignas(16) char as_s[128 * 128];  // [m][n] bf16, swz (m&7)<<4
  const int bid = blockIdx.x;
  const int b = bid & 7;
  const int rest = bid >> 3;
  const int mt = rest & 31;
  const int ot = rest >> 5;
  const int m0 = mt * 128, o0 = ot * 128;
  const int t = threadIdx.x;
  const int w = t >> 6, lane = t & 63;
  const int l4 = lane >> 4, l16 = lane & 15;
  const ushort* vb  = (const ushort*)(wsb + VB_B) + (size_t)b * NC * SN;
  const ushort* qtb = (const ushort*)(wsb + QT_B) + (size_t)b * SN * ND;
  const ushort* ktb = (const ushort*)(wsb + KT_B) + (size_t)b * SN * ND;
  const float Cb = ((const float*)(wsb + C_B))[b];

  // stage resident K^T tile
  {
    int row = t >> 1, db = (t & 1) * 32;
#pragma unroll
    for (int i = 0; i < 2; ++i) {
      int b16 = db + i * 16;
      *reinterpret_cast<uint4*>(kt_s + row * 64 + (b16 ^ ((row & 3) << 4))) =
        *reinterpret_cast<const uint4*>(ktb + (size_t)(m0 + row) * ND + b16 / 2);
    }
  }
  const int s_nf0 = (w & 1) * 2;   // S n-frag base (2 frags)
  const int s_mf0 = (w >> 1) * 4;  // S m-frag base (4 frags)
  const int p_ob = (w & 1) * 64;   // PV o base within block
  const int p_mb = (w >> 1) * 64;  // PV m base within block
  const f32x4 zf = {0.f, 0.f, 0.f, 0.f};
  f32x4 acc[4][4] = {};

  for (int n0 = 0; n0 < SN; n0 += 64) {
    // stage q^T chunk [64][32]
    {
      int row = t >> 2, db = (t & 3) * 16;
      *reinterpret_cast<uint4*>(qt_s + row * 64 + (db ^ ((row & 3) << 4))) =
        *reinterpret_cast<const uint4*>(qtb + (size_t)(n0 + row) * ND + db / 2);
    }
    __syncthreads();
    // S phase: S[64n x 128m], exp, pack to as_s
    short8 afr[2];
#pragma unroll
    for (int i = 0; i < 2; ++i) {
      int nn = (s_nf0 + i) * 16 + l16;
      afr[i] = *reinterpret_cast<const short8*>(qt_s + nn * 64 + ((l4 * 16) ^ ((nn & 3) << 4)));
    }
#pragma unroll
    for (int j = 0; j < 4; ++j) {
      int mm = (s_mf0 + j) * 16 + l16;
      short8 bfr = *reinterpret_cast<const short8*>(kt_s + mm * 64 + ((l4 * 16) ^ ((mm & 3) << 4)));
#pragma unroll
      for (int i = 0; i < 2; ++i) {
        f32x4 sv = __builtin_amdgcn_mfma_f32_16x16x32_bf16(afr[i], bfr, zf, 0, 0, 0);
        uint2 pk;
        pk.x = bfpack(__expf(sv[0] - Cb), __expf(sv[1] - Cb));
        pk.y = bfpack(__expf(sv[2] - Cb), __expf(sv[3] - Cb));
        int nbase = (s_nf0 + i) * 16 + l4 * 4;
        *reinterpret_cast<uint2*>(as_s + mm * 128 + ((nbase * 2) ^ ((mm & 7) << 4))) = pk;
      }
    }
    __syncthreads();
    // PV phase
#pragma unroll
    for (int kk = 0; kk < 2; ++kk) {
      short8 vf[4];
#pragma unroll
      for (int of = 0; of < 4; ++of) {
        int oo = o0 + p_ob + of * 16 + l16;
        vf[of] = *reinterpret_cast<const short8*>(vb + (size_t)oo * SN + n0 + kk * 32 + l4 * 8);
      }
#pragma unroll
      for (int mf = 0; mf < 4; ++mf) {
        int mm = p_mb + mf * 16 + l16;
        short8 af = *reinterpret_cast<const short8*>(
            as_s + mm * 128 + ((kk * 64 + l4 * 16) ^ ((mm & 7) << 4)));
#pragma unroll
        for (int of = 0; of < 4; ++of)
          acc[of][mf] = __builtin_amdgcn_mfma_f32_16x16x32_bf16(vf[of], af, acc[of][mf], 0, 0, 0);
      }
    }
    // next iteration's first barrier protects as_s/qt_s rewrites
  }
  // epilogue: out = acc + x
#pragma unroll
  for (int of = 0; of < 4; ++of)
#pragma unroll
    for (int mf = 0; mf < 4; ++mf) {
      int mm = m0 + p_mb + mf * 16 + l16;
#pragma unroll
      for (int j = 0; j < 4; ++j) {
        int orow = o0 + p_ob + of * 16 + l4 * 4 + j;
        size_t idx = ((size_t)b * NC + orow) * SN + mm;
        out[idx] = acc[of][mf][j] + x[idx];
      }
    }
}

extern "C" void kernel_launch(void* const* d_in, const int* in_sizes, int n_in,
                              void* d_out, int out_size, void* d_ws, size_t ws_size,
                              hipStream_t stream)
{
  const float* x  = (const float*)d_in[0];
  const float* W1 = (const float*)d_in[1];
  const float* b1 = (const float*)d_in[2];
  const float* W2 = (const float*)d_in[3];
  const float* b2 = (const float*)d_in[4];
  const float* W3 = (const float*)d_in[5];
  const float* b3 = (const float*)d_in[6];
  char* wsb  = (char*)d_ws;
  float* out = (float*)d_out;

  proj_kernel<<<dim3(64, 5, NBATCH), 256, 0, stream>>>(x, W1, b1, W2, b2, W3, b3, wsb);
  qk_stats<<<dim3(32, 32, NBATCH), 256, 0, stream>>>(
      wsb, (float*)(wsb + PM_B), (float*)(wsb + PS_B));
  reduce_kernel<<<NBATCH, 256, 0, stream>>>(wsb);
  attn_out<<<512, 256, 0, stream>>>(wsb, x, out);
}

// Round 3
// 236.007 us; speedup vs baseline: 8.0421x; 1.3064x over previous
//
#include <hip/hip_runtime.h>
#include <math.h>

#define NBATCH 8
#define NC 256
#define ND 32
#define SN 4096

// Workspace byte offsets
constexpr size_t VB_B   = 0;                      // 8*256*4096*2 = 16 MB bf16 V [b][o][n]
constexpr size_t QT_B   = 16777216;               // 2 MB bf16 Q^T [b][n][d] (pre-scaled by log2e)
constexpr size_t KT_B   = QT_B + 2097152;         // 2 MB bf16 K^T [b][m][d]
constexpr size_t PM_B   = KT_B + 2097152;         // 8*1024 f32 partial max (exp2 domain)
constexpr size_t PS_B   = PM_B + 32768;           // 8*1024 f32 partial sum2
constexpr size_t C_B    = PS_B + 32768;           // 8 f32: C' = M' + log2(Z')
constexpr size_t WB_B   = C_B + 64;               // 320*256 bf16 = 160 KB packed weights
constexpr size_t BIAS_B = WB_B + 163840;          // 320 f32 biases

typedef __attribute__((ext_vector_type(8))) short short8;
typedef __attribute__((ext_vector_type(4))) float f32x4;

__device__ __forceinline__ unsigned bf16rne(float f) {
  unsigned u = __float_as_uint(f);
  return (u + 0x7fffu + ((u >> 16) & 1u)) >> 16;
}
__device__ __forceinline__ unsigned bfpack(float lo, float hi) {
  return bf16rne(lo) | (bf16rne(hi) << 16);
}

// ---------------------------------------------------------------------------
// Kernel 0: pack W1|W2*log2e|W3 -> bf16 Wb[320][256], biases -> f32[320]
// ---------------------------------------------------------------------------
__global__ __launch_bounds__(256) void prep_kernel(
    const float* __restrict__ W1, const float* __restrict__ b1,
    const float* __restrict__ W2, const float* __restrict__ b2,
    const float* __restrict__ W3, const float* __restrict__ b3,
    char* __restrict__ wsb)
{
  ushort* Wb = (ushort*)(wsb + WB_B);
  float* bias = (float*)(wsb + BIAS_B);
  const float LOG2E = 1.4426950408889634f;
  int idx = blockIdx.x * 256 + threadIdx.x;  // 0..20479 (320 rows x 64 quads)
  int r = idx >> 6, c4 = (idx & 63) * 4;
  float4 v; float sc = 1.0f;
  if (r < 256)      { v = *(const float4*)(W1 + (size_t)r * 256 + c4); }
  else if (r < 288) { v = *(const float4*)(W2 + (size_t)(r - 256) * 256 + c4); sc = LOG2E; }
  else              { v = *(const float4*)(W3 + (size_t)(r - 288) * 256 + c4); }
  ushort4 o;
  o.x = (ushort)bf16rne(v.x * sc); o.y = (ushort)bf16rne(v.y * sc);
  o.z = (ushort)bf16rne(v.z * sc); o.w = (ushort)bf16rne(v.w * sc);
  *(ushort4*)(Wb + (size_t)r * 256 + c4) = o;
  if (blockIdx.x == 0 && threadIdx.x < 320) {
    int q = threadIdx.x;
    bias[q] = q < 256 ? b1[q] : (q < 288 ? b2[q - 256] * LOG2E : b3[q - 288]);
  }
}

// ---------------------------------------------------------------------------
// Kernel 1: MFMA projections. Block: 128 n-cols x all 320 out-rows, 8 waves.
// D[n][o] layout -> V rows get 8B packed stores, q/k go to [n][d] transposed.
// ---------------------------------------------------------------------------
__global__ __launch_bounds__(512) void proj_kernel(
    const float* __restrict__ x, char* __restrict__ wsb)
{
  __shared__ alignas(16) char xT[65536];    // [128 n][256 c] bf16, swz ((n&7)<<4)
  __shared__ alignas(16) char Wsh[40960];   // [320 o][64 c] bf16 chunk, swz ((o&7)<<4)
  const int bid = blockIdx.x;
  const int b = bid & 7, nt = bid >> 3;
  const int n0 = nt * 128;
  const int t = threadIdx.x, w = t >> 6, lane = t & 63;
  const int l4 = lane >> 4, l16 = lane & 15;
  const float* xb = x + (size_t)b * NC * SN;
  const ushort* Wb = (const ushort*)(wsb + WB_B);
  const float* bias = (const float*)(wsb + BIAS_B);
  ushort* vbuf  = (ushort*)(wsb + VB_B);
  ushort* qtbuf = (ushort*)(wsb + QT_B);
  ushort* ktbuf = (ushort*)(wsb + KT_B);

  // stage x^T (fp32 -> bf16, transposed, conflict-free packed-pair writes)
  {
    int cp = w * 16 + l16;       // c-pair 0..127 -> c = 2cp
    int c  = cp * 2;
    int nb0 = l4 * 4;
#pragma unroll
    for (int ni = 0; ni < 8; ++ni) {
      int nB = ni * 16 + nb0;
      float4 a0 = *(const float4*)(xb + (size_t)c * SN + n0 + nB);
      float4 a1 = *(const float4*)(xb + (size_t)(c + 1) * SN + n0 + nB);
      const float* p0 = (const float*)&a0;
      const float* p1 = (const float*)&a1;
#pragma unroll
      for (int j = 0; j < 4; ++j) {
        int n = nB + j;
        *(uint*)(xT + n * 512 + ((cp * 4) ^ ((n & 7) << 4))) = bfpack(p0[j], p1[j]);
      }
    }
  }
  // stage W chunk 0
#pragma unroll
  for (int ii = 0; ii < 5; ++ii) {
    int slot = t + ii * 512;
    int r = slot >> 3, cc = slot & 7;
    *(uint4*)(Wsh + r * 128 + ((cc * 16) ^ ((r & 7) << 4))) =
        *(const uint4*)(Wb + (size_t)r * 256 + cc * 8);
  }
  __syncthreads();

  const int of_g = w >> 1;   // 4 groups x 5 of = 20 output frags (320 rows)
  const int nf_g = w & 1;    // 2 groups x 4 nf = 8 n frags (128 cols)
  f32x4 acc[5][4] = {};

  for (int c4 = 0; c4 < 4; ++c4) {
#pragma unroll
    for (int kk = 0; kk < 2; ++kk) {
      short8 a[4];
#pragma unroll
      for (int nf = 0; nf < 4; ++nf) {
        int n = nf_g * 64 + nf * 16 + l16;
        a[nf] = *(const short8*)(xT + n * 512 +
                 ((c4 * 128 + kk * 64 + l4 * 16) ^ ((n & 7) << 4)));
      }
#pragma unroll
      for (int of = 0; of < 5; ++of) {
        int o = (of_g * 5 + of) * 16 + l16;
        short8 bf = *(const short8*)(Wsh + o * 128 +
                    ((kk * 64 + l4 * 16) ^ ((o & 7) << 4)));
#pragma unroll
        for (int nf = 0; nf < 4; ++nf)
          acc[of][nf] = __builtin_amdgcn_mfma_f32_16x16x32_bf16(a[nf], bf, acc[of][nf], 0, 0, 0);
      }
    }
    if (c4 < 3) {
      __syncthreads();
#pragma unroll
      for (int ii = 0; ii < 5; ++ii) {
        int slot = t + ii * 512;
        int r = slot >> 3, cc = slot & 7;
        *(uint4*)(Wsh + r * 128 + ((cc * 16) ^ ((r & 7) << 4))) =
            *(const uint4*)(Wb + (size_t)r * 256 + (c4 + 1) * 64 + cc * 8);
      }
      __syncthreads();
    }
  }

  // epilogue
#pragma unroll
  for (int of = 0; of < 5; ++of) {
    int o = (of_g * 5 + of) * 16 + l16;
    float bv = bias[o];
#pragma unroll
    for (int nf = 0; nf < 4; ++nf) {
      int nb = nf_g * 64 + nf * 16 + l4 * 4;
      float v0 = acc[of][nf][0] + bv, v1 = acc[of][nf][1] + bv;
      float v2 = acc[of][nf][2] + bv, v3 = acc[of][nf][3] + bv;
      if (o < 256) {
        uint2 pk; pk.x = bfpack(v0, v1); pk.y = bfpack(v2, v3);
        *(uint2*)(vbuf + ((size_t)b * NC + o) * SN + n0 + nb) = pk;
      } else if (o < 288) {
        int d = o - 256;
        qtbuf[((size_t)b * SN + n0 + nb + 0) * ND + d] = (ushort)bf16rne(v0);
        qtbuf[((size_t)b * SN + n0 + nb + 1) * ND + d] = (ushort)bf16rne(v1);
        qtbuf[((size_t)b * SN + n0 + nb + 2) * ND + d] = (ushort)bf16rne(v2);
        qtbuf[((size_t)b * SN + n0 + nb + 3) * ND + d] = (ushort)bf16rne(v3);
      } else {
        int d = o - 288;
        ktbuf[((size_t)b * SN + n0 + nb + 0) * ND + d] = (ushort)bf16rne(v0);
        ktbuf[((size_t)b * SN + n0 + nb + 1) * ND + d] = (ushort)bf16rne(v1);
        ktbuf[((size_t)b * SN + n0 + nb + 2) * ND + d] = (ushort)bf16rne(v2);
        ktbuf[((size_t)b * SN + n0 + nb + 3) * ND + d] = (ushort)bf16rne(v3);
      }
    }
  }
}

// ---------------------------------------------------------------------------
// Kernel 2: QK^T tile stats in exp2 domain. 128n x 128m per block, 4 waves.
// ---------------------------------------------------------------------------
__global__ __launch_bounds__(256) void qk_stats(
    const char* __restrict__ wsb, float* __restrict__ pm, float* __restrict__ ps)
{
  __shared__ alignas(16) char qt_s[128 * 64];
  __shared__ alignas(16) char kt_s[128 * 64];
  __shared__ float wm[4], wz[4];
  const int bid = blockIdx.x;
  const int b = bid & 7, ny = (bid >> 3) & 31, mx = bid >> 8;
  const int n0 = ny * 128, m0 = mx * 128;
  const int t = threadIdx.x, w = t >> 6, lane = t & 63;
  const int l4 = lane >> 4, l16 = lane & 15;
  const ushort* qtb = (const ushort*)(wsb + QT_B) + (size_t)b * SN * ND;
  const ushort* ktb = (const ushort*)(wsb + KT_B) + (size_t)b * SN * ND;
  {
    int row = t >> 1, db = (t & 1) * 32;
#pragma unroll
    for (int i = 0; i < 2; ++i) {
      int b16 = db + i * 16;
      int dst = row * 64 + (b16 ^ ((row & 3) << 4));
      *(uint4*)(qt_s + dst) = *(const uint4*)(qtb + (size_t)(n0 + row) * ND + b16 / 2);
      *(uint4*)(kt_s + dst) = *(const uint4*)(ktb + (size_t)(m0 + row) * ND + b16 / 2);
    }
  }
  __syncthreads();
  const f32x4 zf = {0.f, 0.f, 0.f, 0.f};
  short8 bfr[2];
#pragma unroll
  for (int j = 0; j < 2; ++j) {
    int mm = (w * 2 + j) * 16 + l16;
    bfr[j] = *(const short8*)(kt_s + mm * 64 + ((l4 * 16) ^ ((mm & 3) << 4)));
  }
  f32x4 sfr[8][2];
#pragma unroll
  for (int i = 0; i < 8; ++i) {
    int nn = i * 16 + l16;
    short8 af = *(const short8*)(qt_s + nn * 64 + ((l4 * 16) ^ ((nn & 3) << 4)));
#pragma unroll
    for (int j = 0; j < 2; ++j)
      sfr[i][j] = __builtin_amdgcn_mfma_f32_16x16x32_bf16(af, bfr[j], zf, 0, 0, 0);
  }
  float mt = -1e30f;
#pragma unroll
  for (int i = 0; i < 8; ++i)
#pragma unroll
    for (int j = 0; j < 2; ++j)
#pragma unroll
      for (int r = 0; r < 4; ++r) mt = fmaxf(mt, sfr[i][j][r]);
  float zt = 0.f;
#pragma unroll
  for (int i = 0; i < 8; ++i)
#pragma unroll
    for (int j = 0; j < 2; ++j)
#pragma unroll
      for (int r = 0; r < 4; ++r) zt += exp2f(sfr[i][j][r] - mt);

  // wave shuffle reduce
#pragma unroll
  for (int off = 1; off < 64; off <<= 1) {
    float m2 = __shfl_xor(mt, off);
    float z2 = __shfl_xor(zt, off);
    float M = fmaxf(mt, m2);
    zt = zt * exp2f(mt - M) + z2 * exp2f(m2 - M);
    mt = M;
  }
  if (lane == 0) { wm[w] = mt; wz[w] = zt; }
  __syncthreads();
  if (t == 0) {
    float m = wm[0], z = wz[0];
#pragma unroll
    for (int i = 1; i < 4; ++i) {
      float M = fmaxf(m, wm[i]);
      z = z * exp2f(m - M) + wz[i] * exp2f(wm[i] - M);
      m = M;
    }
    int idx = (b * 32 + ny) * 32 + mx;
    pm[idx] = m; ps[idx] = z;
  }
}

// ---------------------------------------------------------------------------
// Kernel 3: combine partials -> C'_b = M' + log2(Z')
// ---------------------------------------------------------------------------
__global__ __launch_bounds__(256) void reduce_kernel(char* __restrict__ wsb)
{
  const int b = blockIdx.x;
  const float* pm = (const float*)(wsb + PM_B) + (size_t)b * 1024;
  const float* ps = (const float*)(wsb + PS_B) + (size_t)b * 1024;
  const int t = threadIdx.x;
  float m = -1e30f, z = 0.f;
  for (int i = t; i < 1024; i += 256) {
    float m2 = pm[i], z2 = ps[i];
    float M = fmaxf(m, m2);
    z = z * exp2f(m - M) + z2 * exp2f(m2 - M);
    m = M;
  }
#pragma unroll
  for (int off = 1; off < 64; off <<= 1) {
    float m2 = __shfl_xor(m, off);
    float z2 = __shfl_xor(z, off);
    float M = fmaxf(m, m2);
    z = z * exp2f(m - M) + z2 * exp2f(m2 - M);
    m = M;
  }
  __shared__ float wm[4], wz[4];
  int w = t >> 6;
  if ((t & 63) == 0) { wm[w] = m; wz[w] = z; }
  __syncthreads();
  if (t == 0) {
    float M = wm[0], Z = wz[0];
#pragma unroll
    for (int i = 1; i < 4; ++i) {
      float Mn = fmaxf(M, wm[i]);
      Z = Z * exp2f(M - Mn) + wz[i] * exp2f(wm[i] - Mn);
      M = Mn;
    }
    ((float*)(wsb + C_B))[b] = M + log2f(Z);
  }
}

// ---------------------------------------------------------------------------
// Kernel 4: attention output. Block = 256 o x 128 m, 8 waves, chunk n=64.
// Single barrier per chunk, dbuf as_s/qt_s, V prefetched to regs, exp2 softmax.
// ---------------------------------------------------------------------------
__global__ __launch_bounds__(512) void attn_out(
    const char* __restrict__ wsb, const float* __restrict__ x, float* __restrict__ out)
{
  __shared__ alignas(16) char kt_s[16384];      // [128 m][32 d] bf16, swz (m&3)<<4
  __shared__ alignas(16) char qt_s[2][4096];    // [64 n][32 d] bf16, swz (n&3)<<4
  __shared__ alignas(16) char as_s[2][32768];   // [128 m][128 n] bf16, swz (m&7)<<4
  const int bid = blockIdx.x;
  const int b = bid & 7, mt = bid >> 3;
  const int m0 = mt * 128;
  const int t = threadIdx.x, w = t >> 6, lane = t & 63;
  const int l4 = lane >> 4, l16 = lane & 15;
  const ushort* vb  = (const ushort*)(wsb + VB_B) + (size_t)b * NC * SN;
  const ushort* qtb = (const ushort*)(wsb + QT_B) + (size_t)b * SN * ND;
  const ushort* ktb = (const ushort*)(wsb + KT_B) + (size_t)b * SN * ND;
  const float Cb = ((const float*)(wsb + C_B))[b];

  // prologue staging
  {
    int row = t >> 2, sl = t & 3;
    *(uint4*)(kt_s + row * 64 + ((sl * 16) ^ ((row & 3) << 4))) =
        *(const uint4*)(ktb + (size_t)(m0 + row) * ND + sl * 8);
  }
  const int qrow = t >> 3, qsl = t & 7;
  *(uint2*)(qt_s[0] + qrow * 64 + ((qsl * 8) ^ ((qrow & 3) << 4))) =
      *(const uint2*)(qtb + (size_t)qrow * ND + qsl * 4);
  __syncthreads();

  // hoisted K fragment (constant across chunks)
  const int mS = w * 16 + l16;   // S-phase m (this wave's column set)
  short8 bfr = *(const short8*)(kt_s + mS * 64 + ((l4 * 16) ^ ((mS & 3) << 4)));

  const int o_q = (w >> 1) * 64;   // PV o-quad
  const int m_h = (w & 1) * 64;    // PV m-half
  const f32x4 zf = {0.f, 0.f, 0.f, 0.f};
  f32x4 acc[4][4] = {};
  int cur = 0;

  for (int i = 0; i < 64; ++i) {
    const int n0 = i * 64;
    // V prefetch (regs; completes by the barrier)
    short8 vf[2][4];
#pragma unroll
    for (int kk = 0; kk < 2; ++kk)
#pragma unroll
      for (int of = 0; of < 4; ++of)
        vf[kk][of] = *(const short8*)(vb + (size_t)(o_q + of * 16 + l16) * SN +
                                      n0 + kk * 32 + l4 * 8);
    // q^T prefetch for next chunk
    uint2 qnext;
    const bool pf = (i < 63);
    if (pf) qnext = *(const uint2*)(qtb + (size_t)(n0 + 64 + qrow) * ND + qsl * 4);

    // S phase: this wave's 16 m-cols x 64 n
    {
      short8 afr[4];
#pragma unroll
      for (int nf = 0; nf < 4; ++nf) {
        int n = nf * 16 + l16;
        afr[nf] = *(const short8*)(qt_s[cur] + n * 64 + ((l4 * 16) ^ ((n & 3) << 4)));
      }
#pragma unroll
      for (int nf = 0; nf < 4; ++nf) {
        f32x4 sv = __builtin_amdgcn_mfma_f32_16x16x32_bf16(afr[nf], bfr, zf, 0, 0, 0);
        uint2 pk;
        pk.x = bfpack(exp2f(sv[0] - Cb), exp2f(sv[1] - Cb));
        pk.y = bfpack(exp2f(sv[2] - Cb), exp2f(sv[3] - Cb));
        int nb2 = (nf * 16 + l4 * 4) * 2;
        *(uint2*)(as_s[cur] + mS * 256 + (nb2 ^ ((mS & 7) << 4))) = pk;
      }
    }
    if (pf)
      *(uint2*)(qt_s[cur ^ 1] + qrow * 64 + ((qsl * 8) ^ ((qrow & 3) << 4))) = qnext;
    __syncthreads();

    // PV phase: o-quad x m-half
#pragma unroll
    for (int kk = 0; kk < 2; ++kk) {
#pragma unroll
      for (int mf = 0; mf < 4; ++mf) {
        int m = m_h + mf * 16 + l16;
        short8 af = *(const short8*)(as_s[cur] + m * 256 +
                     ((kk * 64 + l4 * 16) ^ ((m & 7) << 4)));
#pragma unroll
        for (int of = 0; of < 4; ++of)
          acc[of][mf] = __builtin_amdgcn_mfma_f32_16x16x32_bf16(vf[kk][of], af, acc[of][mf], 0, 0, 0);
      }
    }
    cur ^= 1;
  }

  // epilogue: out = acc + x
#pragma unroll
  for (int of = 0; of < 4; ++of)
#pragma unroll
    for (int mf = 0; mf < 4; ++mf) {
      int mg = m0 + m_h + mf * 16 + l16;
#pragma unroll
      for (int j = 0; j < 4; ++j) {
        int o = o_q + of * 16 + l4 * 4 + j;
        size_t idx = ((size_t)b * NC + o) * SN + mg;
        out[idx] = acc[of][mf][j] + x[idx];
      }
    }
}

extern "C" void kernel_launch(void* const* d_in, const int* in_sizes, int n_in,
                              void* d_out, int out_size, void* d_ws, size_t ws_size,
                              hipStream_t stream)
{
  const float* x  = (const float*)d_in[0];
  const float* W1 = (const float*)d_in[1];
  const float* b1 = (const float*)d_in[2];
  const float* W2 = (const float*)d_in[3];
  const float* b2 = (const float*)d_in[4];
  const float* W3 = (const float*)d_in[5];
  const float* b3 = (const float*)d_in[6];
  char* wsb  = (char*)d_ws;
  float* out = (float*)d_out;

  prep_kernel<<<80, 256, 0, stream>>>(W1, b1, W2, b2, W3, b3, wsb);
  proj_kernel<<<256, 512, 0, stream>>>(x, wsb);
  qk_stats<<<8192, 256, 0, stream>>>(wsb, (float*)(wsb + PM_B), (float*)(wsb + PS_B));
  reduce_kernel<<<NBATCH, 256, 0, stream>>>(wsb);
  attn_out<<<256, 512, 0, stream>>>(wsb, x, out);
}

// Round 4
// 210.571 us; speedup vs baseline: 9.0136x; 1.1208x over previous
//
#include <hip/hip_runtime.h>
#include <hip/hip_bf16.h>
#include <math.h>

#define NBATCH 8
#define NC 256
#define ND 32
#define SN 4096

// Workspace byte offsets
constexpr size_t VB_B   = 0;                      // 16 MB bf16 V [b][o][n]
constexpr size_t QT_B   = 16777216;               // 2 MB bf16 Q^T [b][n][d] (pre-scaled by log2e)
constexpr size_t KT_B   = QT_B + 2097152;         // 2 MB bf16 K^T [b][m][d]
constexpr size_t PM_B   = KT_B + 2097152;         // partial max (exp2 domain)
constexpr size_t PS_B   = PM_B + 32768;           // partial sum2
constexpr size_t C_B    = PS_B + 32768;           // 8 f32: C' = M' + log2(Z')
constexpr size_t WB_B   = C_B + 64;               // 320*256 bf16 packed weights
constexpr size_t BIAS_B = WB_B + 163840;          // 320 f32 biases

typedef __attribute__((ext_vector_type(8))) short short8;
typedef __attribute__((ext_vector_type(4))) float f32x4;

__device__ __forceinline__ unsigned bf16rne(float f) {
  unsigned u = __float_as_uint(f);
  return (u + 0x7fffu + ((u >> 16) & 1u)) >> 16;
}
__device__ __forceinline__ unsigned bfpack2(float lo, float hi) {
  union { __hip_bfloat162 h; unsigned u; } cv;
  cv.h.x = __float2bfloat16(lo);
  cv.h.y = __float2bfloat16(hi);
  return cv.u;
}

// ---------------------------------------------------------------------------
// Kernel 0: pack W1|W2*log2e|W3 -> bf16 Wb[320][256], biases -> f32[320]
// ---------------------------------------------------------------------------
__global__ __launch_bounds__(256) void prep_kernel(
    const float* __restrict__ W1, const float* __restrict__ b1,
    const float* __restrict__ W2, const float* __restrict__ b2,
    const float* __restrict__ W3, const float* __restrict__ b3,
    char* __restrict__ wsb)
{
  ushort* Wb = (ushort*)(wsb + WB_B);
  float* bias = (float*)(wsb + BIAS_B);
  const float LOG2E = 1.4426950408889634f;
  int idx = blockIdx.x * 256 + threadIdx.x;
  int r = idx >> 6, c4 = (idx & 63) * 4;
  float4 v; float sc = 1.0f;
  if (r < 256)      { v = *(const float4*)(W1 + (size_t)r * 256 + c4); }
  else if (r < 288) { v = *(const float4*)(W2 + (size_t)(r - 256) * 256 + c4); sc = LOG2E; }
  else              { v = *(const float4*)(W3 + (size_t)(r - 288) * 256 + c4); }
  ushort4 o;
  o.x = (ushort)bfpack2(v.x * sc, 0.f); o.y = (ushort)bfpack2(v.y * sc, 0.f);
  o.z = (ushort)bfpack2(v.z * sc, 0.f); o.w = (ushort)bfpack2(v.w * sc, 0.f);
  *(ushort4*)(Wb + (size_t)r * 256 + c4) = o;
  if (blockIdx.x == 0 && threadIdx.x < 320) {
    int q = threadIdx.x;
    bias[q] = q < 256 ? b1[q] : (q < 288 ? b2[q - 256] * LOG2E : b3[q - 288]);
  }
}

// ---------------------------------------------------------------------------
// Kernel 1: MFMA projections (unchanged structure from round 3)
// ---------------------------------------------------------------------------
__global__ __launch_bounds__(512) void proj_kernel(
    const float* __restrict__ x, char* __restrict__ wsb)
{
  __shared__ alignas(16) char xT[65536];    // [128 n][256 c] bf16, swz ((n&7)<<4)
  __shared__ alignas(16) char Wsh[40960];   // [320 o][64 c] bf16 chunk, swz ((o&7)<<4)
  const int bid = blockIdx.x;
  const int b = bid & 7, nt = bid >> 3;
  const int n0 = nt * 128;
  const int t = threadIdx.x, w = t >> 6, lane = t & 63;
  const int l4 = lane >> 4, l16 = lane & 15;
  const float* xb = x + (size_t)b * NC * SN;
  const ushort* Wb = (const ushort*)(wsb + WB_B);
  const float* bias = (const float*)(wsb + BIAS_B);
  ushort* vbuf  = (ushort*)(wsb + VB_B);
  ushort* qtbuf = (ushort*)(wsb + QT_B);
  ushort* ktbuf = (ushort*)(wsb + KT_B);

  {
    int cp = w * 16 + l16;
    int c  = cp * 2;
    int nb0 = l4 * 4;
#pragma unroll
    for (int ni = 0; ni < 8; ++ni) {
      int nB = ni * 16 + nb0;
      float4 a0 = *(const float4*)(xb + (size_t)c * SN + n0 + nB);
      float4 a1 = *(const float4*)(xb + (size_t)(c + 1) * SN + n0 + nB);
      const float* p0 = (const float*)&a0;
      const float* p1 = (const float*)&a1;
#pragma unroll
      for (int j = 0; j < 4; ++j) {
        int n = nB + j;
        *(uint*)(xT + n * 512 + ((cp * 4) ^ ((n & 7) << 4))) = bfpack2(p0[j], p1[j]);
      }
    }
  }
#pragma unroll
  for (int ii = 0; ii < 5; ++ii) {
    int slot = t + ii * 512;
    int r = slot >> 3, cc = slot & 7;
    *(uint4*)(Wsh + r * 128 + ((cc * 16) ^ ((r & 7) << 4))) =
        *(const uint4*)(Wb + (size_t)r * 256 + cc * 8);
  }
  __syncthreads();

  const int of_g = w >> 1;
  const int nf_g = w & 1;
  f32x4 acc[5][4] = {};

  for (int c4 = 0; c4 < 4; ++c4) {
#pragma unroll
    for (int kk = 0; kk < 2; ++kk) {
      short8 a[4];
#pragma unroll
      for (int nf = 0; nf < 4; ++nf) {
        int n = nf_g * 64 + nf * 16 + l16;
        a[nf] = *(const short8*)(xT + n * 512 +
                 ((c4 * 128 + kk * 64 + l4 * 16) ^ ((n & 7) << 4)));
      }
#pragma unroll
      for (int of = 0; of < 5; ++of) {
        int o = (of_g * 5 + of) * 16 + l16;
        short8 bf = *(const short8*)(Wsh + o * 128 +
                    ((kk * 64 + l4 * 16) ^ ((o & 7) << 4)));
#pragma unroll
        for (int nf = 0; nf < 4; ++nf)
          acc[of][nf] = __builtin_amdgcn_mfma_f32_16x16x32_bf16(a[nf], bf, acc[of][nf], 0, 0, 0);
      }
    }
    if (c4 < 3) {
      __syncthreads();
#pragma unroll
      for (int ii = 0; ii < 5; ++ii) {
        int slot = t + ii * 512;
        int r = slot >> 3, cc = slot & 7;
        *(uint4*)(Wsh + r * 128 + ((cc * 16) ^ ((r & 7) << 4))) =
            *(const uint4*)(Wb + (size_t)r * 256 + (c4 + 1) * 64 + cc * 8);
      }
      __syncthreads();
    }
  }

#pragma unroll
  for (int of = 0; of < 5; ++of) {
    int o = (of_g * 5 + of) * 16 + l16;
    float bv = bias[o];
#pragma unroll
    for (int nf = 0; nf < 4; ++nf) {
      int nb = nf_g * 64 + nf * 16 + l4 * 4;
      float v0 = acc[of][nf][0] + bv, v1 = acc[of][nf][1] + bv;
      float v2 = acc[of][nf][2] + bv, v3 = acc[of][nf][3] + bv;
      if (o < 256) {
        uint2 pk; pk.x = bfpack2(v0, v1); pk.y = bfpack2(v2, v3);
        *(uint2*)(vbuf + ((size_t)b * NC + o) * SN + n0 + nb) = pk;
      } else if (o < 288) {
        int d = o - 256;
        qtbuf[((size_t)b * SN + n0 + nb + 0) * ND + d] = (ushort)bf16rne(v0);
        qtbuf[((size_t)b * SN + n0 + nb + 1) * ND + d] = (ushort)bf16rne(v1);
        qtbuf[((size_t)b * SN + n0 + nb + 2) * ND + d] = (ushort)bf16rne(v2);
        qtbuf[((size_t)b * SN + n0 + nb + 3) * ND + d] = (ushort)bf16rne(v3);
      } else {
        int d = o - 288;
        ktbuf[((size_t)b * SN + n0 + nb + 0) * ND + d] = (ushort)bf16rne(v0);
        ktbuf[((size_t)b * SN + n0 + nb + 1) * ND + d] = (ushort)bf16rne(v1);
        ktbuf[((size_t)b * SN + n0 + nb + 2) * ND + d] = (ushort)bf16rne(v2);
        ktbuf[((size_t)b * SN + n0 + nb + 3) * ND + d] = (ushort)bf16rne(v3);
      }
    }
  }
}

// ---------------------------------------------------------------------------
// Kernel 2: QK^T tile stats in exp2 domain (unchanged from round 3)
// ---------------------------------------------------------------------------
__global__ __launch_bounds__(256) void qk_stats(
    const char* __restrict__ wsb, float* __restrict__ pm, float* __restrict__ ps)
{
  __shared__ alignas(16) char qt_s[128 * 64];
  __shared__ alignas(16) char kt_s[128 * 64];
  __shared__ float wm[4], wz[4];
  const int bid = blockIdx.x;
  const int b = bid & 7, ny = (bid >> 3) & 31, mx = bid >> 8;
  const int n0 = ny * 128, m0 = mx * 128;
  const int t = threadIdx.x, w = t >> 6, lane = t & 63;
  const int l4 = lane >> 4, l16 = lane & 15;
  const ushort* qtb = (const ushort*)(wsb + QT_B) + (size_t)b * SN * ND;
  const ushort* ktb = (const ushort*)(wsb + KT_B) + (size_t)b * SN * ND;
  {
    int row = t >> 1, db = (t & 1) * 32;
#pragma unroll
    for (int i = 0; i < 2; ++i) {
      int b16 = db + i * 16;
      int dst = row * 64 + (b16 ^ ((row & 3) << 4));
      *(uint4*)(qt_s + dst) = *(const uint4*)(qtb + (size_t)(n0 + row) * ND + b16 / 2);
      *(uint4*)(kt_s + dst) = *(const uint4*)(ktb + (size_t)(m0 + row) * ND + b16 / 2);
    }
  }
  __syncthreads();
  const f32x4 zf = {0.f, 0.f, 0.f, 0.f};
  short8 bfr[2];
#pragma unroll
  for (int j = 0; j < 2; ++j) {
    int mm = (w * 2 + j) * 16 + l16;
    bfr[j] = *(const short8*)(kt_s + mm * 64 + ((l4 * 16) ^ ((mm & 3) << 4)));
  }
  f32x4 sfr[8][2];
#pragma unroll
  for (int i = 0; i < 8; ++i) {
    int nn = i * 16 + l16;
    short8 af = *(const short8*)(qt_s + nn * 64 + ((l4 * 16) ^ ((nn & 3) << 4)));
#pragma unroll
    for (int j = 0; j < 2; ++j)
      sfr[i][j] = __builtin_amdgcn_mfma_f32_16x16x32_bf16(af, bfr[j], zf, 0, 0, 0);
  }
  float mt = -1e30f;
#pragma unroll
  for (int i = 0; i < 8; ++i)
#pragma unroll
    for (int j = 0; j < 2; ++j)
#pragma unroll
      for (int r = 0; r < 4; ++r) mt = fmaxf(mt, sfr[i][j][r]);
  float zt = 0.f;
#pragma unroll
  for (int i = 0; i < 8; ++i)
#pragma unroll
    for (int j = 0; j < 2; ++j)
#pragma unroll
      for (int r = 0; r < 4; ++r) zt += exp2f(sfr[i][j][r] - mt);

#pragma unroll
  for (int off = 1; off < 64; off <<= 1) {
    float m2 = __shfl_xor(mt, off);
    float z2 = __shfl_xor(zt, off);
    float M = fmaxf(mt, m2);
    zt = zt * exp2f(mt - M) + z2 * exp2f(m2 - M);
    mt = M;
  }
  if (lane == 0) { wm[w] = mt; wz[w] = zt; }
  __syncthreads();
  if (t == 0) {
    float m = wm[0], z = wz[0];
#pragma unroll
    for (int i = 1; i < 4; ++i) {
      float M = fmaxf(m, wm[i]);
      z = z * exp2f(m - M) + wz[i] * exp2f(wm[i] - M);
      m = M;
    }
    int idx = (b * 32 + ny) * 32 + mx;
    pm[idx] = m; ps[idx] = z;
  }
}

// ---------------------------------------------------------------------------
// Kernel 3: combine partials -> C'_b = M' + log2(Z')
// ---------------------------------------------------------------------------
__global__ __launch_bounds__(256) void reduce_kernel(char* __restrict__ wsb)
{
  const int b = blockIdx.x;
  const float* pm = (const float*)(wsb + PM_B) + (size_t)b * 1024;
  const float* ps = (const float*)(wsb + PS_B) + (size_t)b * 1024;
  const int t = threadIdx.x;
  float m = -1e30f, z = 0.f;
  for (int i = t; i < 1024; i += 256) {
    float m2 = pm[i], z2 = ps[i];
    float M = fmaxf(m, m2);
    z = z * exp2f(m - M) + z2 * exp2f(m2 - M);
    m = M;
  }
#pragma unroll
  for (int off = 1; off < 64; off <<= 1) {
    float m2 = __shfl_xor(m, off);
    float z2 = __shfl_xor(z, off);
    float M = fmaxf(m, m2);
    z = z * exp2f(m - M) + z2 * exp2f(m2 - M);
    m = M;
  }
  __shared__ float wm[4], wz[4];
  int w = t >> 6;
  if ((t & 63) == 0) { wm[w] = m; wz[w] = z; }
  __syncthreads();
  if (t == 0) {
    float M = wm[0], Z = wz[0];
#pragma unroll
    for (int i = 1; i < 4; ++i) {
      float Mn = fmaxf(M, wm[i]);
      Z = Z * exp2f(M - Mn) + wz[i] * exp2f(wm[i] - Mn);
      M = Mn;
    }
    ((float*)(wsb + C_B))[b] = M + log2f(Z);
  }
}

// ---------------------------------------------------------------------------
// Kernel 4: attention output. Block = 256 o x 64 m, 8 waves, chunk n=128.
// 2 blocks/CU. Wave = 32-o slice x all 64 m -> V loaded exactly once/block.
// ---------------------------------------------------------------------------
__global__ __launch_bounds__(512, 4) void attn_out(
    const char* __restrict__ wsb, const float* __restrict__ x, float* __restrict__ out)
{
  __shared__ alignas(16) char kt_s[4096];        // [64 m][32 d] bf16, swz (m&3)<<4
  __shared__ alignas(16) char qt_s[2][8192];     // [128 n][32 d] bf16, swz (n&3)<<4
  __shared__ alignas(16) char as_s[2][16384];    // [64 m][128 n] bf16, swz (m&7)<<4
  const int bid = blockIdx.x;
  const int b = bid & 7, mt = bid >> 3;          // mt 0..63
  const int m0 = mt * 64;
  const int t = threadIdx.x, w = t >> 6, lane = t & 63;
  const int l4 = lane >> 4, l16 = lane & 15;
  const ushort* vb  = (const ushort*)(wsb + VB_B) + (size_t)b * NC * SN;
  const ushort* qtb = (const ushort*)(wsb + QT_B) + (size_t)b * SN * ND;
  const ushort* ktb = (const ushort*)(wsb + KT_B) + (size_t)b * SN * ND;
  const float Cb = ((const float*)(wsb + C_B))[b];

  // stage K^T tile [64][32] (threads 0..255)
  if (t < 256) {
    int row = t >> 2, sl = t & 3;
    *(uint4*)(kt_s + row * 64 + ((sl * 16) ^ ((row & 3) << 4))) =
        *(const uint4*)(ktb + (size_t)(m0 + row) * ND + sl * 8);
  }
  // stage q chunk 0 [128][32]
  const int qrow = t >> 2, qsl = t & 3;
  *(uint4*)(qt_s[0] + qrow * 64 + ((qsl * 16) ^ ((qrow & 3) << 4))) =
      *(const uint4*)(qtb + (size_t)qrow * ND + qsl * 8);
  __syncthreads();

  // S-phase role: fixed m-frag per wave, n-half per wave group
  const int mS = (w & 3) * 16 + l16;
  const int nh_s = w >> 2;
  short8 bfr = *(const short8*)(kt_s + mS * 64 + ((l4 * 16) ^ ((mS & 3) << 4)));

  // V pointers: wave owns o-slice [w*32, w*32+32)
  const ushort* vp0 = vb + (size_t)(w * 32 + l16) * SN + l4 * 8;
  const ushort* vp1 = vp0 + (size_t)16 * SN;

  const f32x4 zf = {0.f, 0.f, 0.f, 0.f};
  f32x4 acc[2][4] = {};
  int cur = 0;

  for (int i = 0; i < 32; ++i) {
    // V prefetch for this chunk (completes by the barrier)
    short8 vf[2][4];
#pragma unroll
    for (int kk = 0; kk < 4; ++kk) {
      vf[0][kk] = *(const short8*)(vp0 + kk * 32);
      vf[1][kk] = *(const short8*)(vp1 + kk * 32);
    }
    vp0 += 128; vp1 += 128;
    // q^T prefetch for next chunk
    uint4 qnext;
    const bool pf = (i < 31);
    if (pf) qnext = *(const uint4*)(qtb + (size_t)((i + 1) * 128 + qrow) * ND + qsl * 8);

    // S phase: this wave's 16 m-cols x 64-n half
#pragma unroll
    for (int ii = 0; ii < 4; ++ii) {
      int nf = nh_s * 4 + ii;
      int n = nf * 16 + l16;
      short8 af = *(const short8*)(qt_s[cur] + n * 64 + ((l4 * 16) ^ ((n & 3) << 4)));
      f32x4 sv = __builtin_amdgcn_mfma_f32_16x16x32_bf16(af, bfr, zf, 0, 0, 0);
      uint2 pk;
      pk.x = bfpack2(exp2f(sv[0] - Cb), exp2f(sv[1] - Cb));
      pk.y = bfpack2(exp2f(sv[2] - Cb), exp2f(sv[3] - Cb));
      int nb2 = (nf * 16 + l4 * 4) * 2;
      *(uint2*)(as_s[cur] + mS * 256 + (nb2 ^ ((mS & 7) << 4))) = pk;
    }
    if (pf)
      *(uint4*)(qt_s[cur ^ 1] + qrow * 64 + ((qsl * 16) ^ ((qrow & 3) << 4))) = qnext;
    __syncthreads();

    // PV phase: 32 MFMAs over o-slice x 64 m
    __builtin_amdgcn_s_setprio(1);
#pragma unroll
    for (int kk = 0; kk < 4; ++kk) {
#pragma unroll
      for (int mf = 0; mf < 4; ++mf) {
        int m = mf * 16 + l16;
        short8 paf = *(const short8*)(as_s[cur] + m * 256 +
                      ((kk * 64 + l4 * 16) ^ ((m & 7) << 4)));
        acc[0][mf] = __builtin_amdgcn_mfma_f32_16x16x32_bf16(vf[0][kk], paf, acc[0][mf], 0, 0, 0);
        acc[1][mf] = __builtin_amdgcn_mfma_f32_16x16x32_bf16(vf[1][kk], paf, acc[1][mf], 0, 0, 0);
      }
    }
    __builtin_amdgcn_s_setprio(0);
    cur ^= 1;
  }

  // epilogue: out = acc + x
#pragma unroll
  for (int of = 0; of < 2; ++of)
#pragma unroll
    for (int mf = 0; mf < 4; ++mf) {
      int m = m0 + mf * 16 + l16;
#pragma unroll
      for (int j = 0; j < 4; ++j) {
        int o = w * 32 + of * 16 + l4 * 4 + j;
        size_t idx = ((size_t)b * NC + o) * SN + m;
        out[idx] = acc[of][mf][j] + x[idx];
      }
    }
}

extern "C" void kernel_launch(void* const* d_in, const int* in_sizes, int n_in,
                              void* d_out, int out_size, void* d_ws, size_t ws_size,
                              hipStream_t stream)
{
  const float* x  = (const float*)d_in[0];
  const float* W1 = (const float*)d_in[1];
  const float* b1 = (const float*)d_in[2];
  const float* W2 = (const float*)d_in[3];
  const float* b2 = (const float*)d_in[4];
  const float* W3 = (const float*)d_in[5];
  const float* b3 = (const float*)d_in[6];
  char* wsb  = (char*)d_ws;
  float* out = (float*)d_out;

  prep_kernel<<<80, 256, 0, stream>>>(W1, b1, W2, b2, W3, b3, wsb);
  proj_kernel<<<256, 512, 0, stream>>>(x, wsb);
  qk_stats<<<8192, 256, 0, stream>>>(wsb, (float*)(wsb + PM_B), (float*)(wsb + PS_B));
  reduce_kernel<<<NBATCH, 256, 0, stream>>>(wsb);
  attn_out<<<512, 512, 0, stream>>>(wsb, x, out);
}